// Round 7
// baseline (122.085 us; speedup 1.0000x reference)
//
#include <hip/hip_runtime.h>

#define N_NODES 50000
#define N_EDGES 800000
#define D 128

#define NTILE 128
#define EPT (N_EDGES / NTILE)     // 6250 edges per tile
#define HALF 25000                // nodes per half-range (LDS pass)

typedef __attribute__((ext_vector_type(8))) short bf16x8;
typedef __attribute__((ext_vector_type(4))) float f32x4;

// ---------------- workspace layout (bytes) ----------------
static const size_t OFF_FLAG = 0;          // int[49] lookback flags (zeroed each call)
static const size_t OFF_PART = 256;        // int[49] block totals (flag-gated)
static const size_t OFF_DEG  = 512;        // int[50000]
static const size_t OFF_OFFS = 200704;     // int[50000]
static const size_t OFF_INV  = 400896;     // float[50000]
static const size_t OFF_WT   = 601088;     // ushort[128*128] bf16 W^T [n][k]
static const size_t OFF_H    = 633856;     // ushort[NTILE][N_NODES] per-tile counts
static const size_t OFF_BR   = 13433856;   // ushort[NTILE][N_NODES] tile-prefix per node
static const size_t OFF_CSR  = 26233856;   // ushort[800000]
static const size_t OFF_XWB  = 27833856;   // ushort[50000*128] bf16
// total: 40,633,856 bytes (ws is 256 MiB)

#define SCAN_B 1024
#define SCAN_NB ((N_NODES + SCAN_B - 1) / SCAN_B)   // 49
#define BM 64
#define NB_GEMM ((N_NODES + BM - 1) / BM)           // 782

__device__ __forceinline__ unsigned short f2bf(float f) {
    unsigned int u = __float_as_uint(f);
    unsigned int r = (u + 0x7fffu + ((u >> 16) & 1u)) >> 16;   // RNE
    return (unsigned short)r;
}
__device__ __forceinline__ float bflo(unsigned int u) { return __uint_as_float(u << 16); }
__device__ __forceinline__ float bfhi(unsigned int u) { return __uint_as_float(u & 0xffff0000u); }

// ---- init: zero lookback flags, convert Wt[n][k] = bf16(W[k][n]) ----
__global__ void k_init(int* __restrict__ flag, const float* __restrict__ W,
                       unsigned short* __restrict__ Wt) {
    int bid = blockIdx.x, t = threadIdx.x;
    if (bid == 0) {
        if (t < 49) flag[t] = 0;
    } else {
        int idx = (bid - 1) * 256 + t;   // 0..16383
        int n = idx >> 7, k = idx & 127;
        Wt[n * D + k] = f2bf(W[k * D + n]);
    }
}

// ---- per-tile node histogram via packed LDS atomics (workgroup scope) ----
// h[n>>1]: low halfword counts even node, high counts odd. Max/tile = 6250 < 65536.
__global__ __launch_bounds__(256) void k_hist(const int* __restrict__ dst,
                                              unsigned short* __restrict__ H) {
    __shared__ unsigned int h[HALF / 2];   // 50 KB
    int tile = blockIdx.x, t = threadIdx.x;
    int e0 = tile * EPT;
    #pragma unroll
    for (int half = 0; half < 2; ++half) {
        int lo = half * HALF;
        for (int i = t; i < HALF / 2; i += 256) h[i] = 0;
        __syncthreads();
        for (int e = e0 + t; e < e0 + EPT; e += 256) {
            int dl = dst[e] - lo;
            if ((unsigned)dl < (unsigned)HALF)
                atomicAdd(&h[dl >> 1], 1u << ((dl & 1) * 16));
        }
        __syncthreads();
        unsigned int* Ht = (unsigned int*)(H + (size_t)tile * N_NODES + lo);
        for (int i = t; i < HALF / 2; i += 256) Ht[i] = h[i];
        __syncthreads();
    }
}

// ---- per-node running sum over tiles: base_rel[t][n], deg[n] ----
__global__ __launch_bounds__(256) void k_base(const unsigned short* __restrict__ H,
                                              unsigned short* __restrict__ br,
                                              int* __restrict__ deg) {
    int n = blockIdx.x * 256 + threadIdx.x;
    if (n >= N_NODES) return;
    int run = 0;
    #pragma unroll 8
    for (int tt = 0; tt < NTILE; ++tt) {
        int c = H[(size_t)tt * N_NODES + n];
        br[(size_t)tt * N_NODES + n] = (unsigned short)run;
        run += c;
    }
    deg[n] = run;
}

// ---- single-launch scan (decoupled lookback, 49 co-resident blocks) ----
__global__ __launch_bounds__(1024) void k_scan(const int* __restrict__ deg,
                                               int* __restrict__ part,
                                               int* __restrict__ flag,
                                               int* __restrict__ offs,
                                               float* __restrict__ inv) {
    int b = blockIdx.x;
    int t = threadIdx.x;
    int i = b * SCAN_B + t;
    int v = (i < N_NODES) ? deg[i] : 0;
    int s = v;
    #pragma unroll
    for (int d = 1; d < 64; d <<= 1) {
        int u = __shfl_up(s, d, 64);
        if ((t & 63) >= d) s += u;
    }
    __shared__ int wsum[16];
    __shared__ int s_prefix;
    if ((t & 63) == 63) wsum[t >> 6] = s;
    __syncthreads();
    if (t < 64) {
        int val = (t < 16) ? wsum[t] : 0;
        int sc = val;
        #pragma unroll
        for (int d = 1; d < 16; d <<= 1) {
            int u = __shfl_up(sc, d, 64);
            if (t >= d) sc += u;
        }
        if (t < 16) wsum[t] = sc - val;     // exclusive over waves
        int total = __shfl(sc, 15, 64);     // block total
        if (t == 0) {
            part[b] = total;
            __threadfence();
            atomicExch(&flag[b], 1);
        }
        int pv = 0;
        if (t < b) {
            while (atomicAdd(&flag[t], 0) == 0) { }
        }
        __threadfence();
        if (t < b) pv = atomicAdd(&part[t], 0);
        #pragma unroll
        for (int off = 32; off >= 1; off >>= 1) pv += __shfl_down(pv, off, 64);
        if (t == 0) s_prefix = pv;
    }
    __syncthreads();
    if (i < N_NODES) {
        offs[i] = s - v + wsum[t >> 6] + s_prefix;
        inv[i] = rsqrtf((float)v + 1.0f);
    }
}

// ---- CSR fill: LDS rank capture + 2B scatter (no global atomics) ----
__global__ __launch_bounds__(256) void k_csr(const int* __restrict__ src,
                                             const int* __restrict__ dst,
                                             const int* __restrict__ offs,
                                             const unsigned short* __restrict__ brAll,
                                             unsigned short* __restrict__ csr) {
    __shared__ unsigned int h[HALF / 2];   // 50 KB
    int tile = blockIdx.x, t = threadIdx.x;
    int e0 = tile * EPT;
    const unsigned short* br = brAll + (size_t)tile * N_NODES;
    #pragma unroll
    for (int half = 0; half < 2; ++half) {
        int lo = half * HALF;
        for (int i = t; i < HALF / 2; i += 256) h[i] = 0;
        __syncthreads();
        for (int e = e0 + t; e < e0 + EPT; e += 256) {
            int d = dst[e];
            int dl = d - lo;
            if ((unsigned)dl < (unsigned)HALF) {
                int sh = (dl & 1) * 16;
                unsigned int old = atomicAdd(&h[dl >> 1], 1u << sh);
                int rank = (old >> sh) & 0xffff;
                csr[offs[d] + (int)br[d] + rank] = (unsigned short)src[e];
            }
        }
        __syncthreads();
    }
}

// ---- pure MFMA GEMM: XW(bf16) = X @ W, XOR-swizzled LDS ----
__global__ __launch_bounds__(256) void k_gemm(const float* __restrict__ X,
                                              const unsigned short* __restrict__ Wt,
                                              unsigned short* __restrict__ XWb) {
    __shared__ unsigned short sA[BM * D];    // 16KB swizzled [row][k]
    __shared__ unsigned short sB[D * D];     // 32KB swizzled [n][k]
    int t = threadIdx.x;
    int r0 = blockIdx.x * BM;

    #pragma unroll
    for (int p = 0; p < 8; ++p) {
        int e = p * 2048 + t * 8;
        int n = e >> 7, k = e & 127;
        uint4 v = *(const uint4*)&Wt[e];
        int idx = n * D + (((k >> 3) ^ (n & 7)) << 3);
        *(uint4*)&sB[idx] = v;
    }
    #pragma unroll
    for (int p = 0; p < 8; ++p) {
        int e = p * 1024 + t * 4;
        int r = e >> 7, c = e & 127;
        int row = r0 + r;
        float4 xv = make_float4(0.f, 0.f, 0.f, 0.f);
        if (row < N_NODES) xv = *(const float4*)&X[row * D + c];
        ushort4 bv;
        bv.x = f2bf(xv.x); bv.y = f2bf(xv.y); bv.z = f2bf(xv.z); bv.w = f2bf(xv.w);
        int idx = r * D + (((c >> 3) ^ (r & 7)) << 3) + (c & 7);
        *(ushort4*)&sA[idx] = bv;
    }
    __syncthreads();

    int w = t >> 6, l = t & 63;
    int arow = w * 16 + (l & 15);
    f32x4 acc[8];
    #pragma unroll
    for (int i = 0; i < 8; ++i) acc[i] = (f32x4){0.f, 0.f, 0.f, 0.f};

    #pragma unroll
    for (int kk = 0; kk < 4; ++kk) {
        int g = kk * 4 + (l >> 4);
        bf16x8 a = *(bf16x8*)&sA[arow * D + ((g ^ (arow & 7)) << 3)];
        #pragma unroll
        for (int nt = 0; nt < 8; ++nt) {
            int nrow = nt * 16 + (l & 15);
            bf16x8 b = *(bf16x8*)&sB[nrow * D + ((g ^ (nrow & 7)) << 3)];
            acc[nt] = __builtin_amdgcn_mfma_f32_16x16x32_bf16(a, b, acc[nt], 0, 0, 0);
        }
    }

    #pragma unroll
    for (int nt = 0; nt < 8; ++nt) {
        #pragma unroll
        for (int r = 0; r < 4; ++r) {
            int m = r0 + w * 16 + (l >> 4) * 4 + r;
            if (m < N_NODES) XWb[m * D + nt * 16 + (l & 15)] = f2bf(acc[nt][r]);
        }
    }
}

// ---- aggregate (bf16 gather, f32 out), 4-deep gather pipeline ----
__global__ __launch_bounds__(256) void k_agg(const unsigned short* __restrict__ XWb,
                                             const unsigned short* __restrict__ csr,
                                             const int* __restrict__ offs,
                                             const int* __restrict__ deg,
                                             const float* __restrict__ inv,
                                             float* __restrict__ out) {
    int node = blockIdx.x * 4 + (threadIdx.x >> 6);
    if (node >= N_NODES) return;
    int l = threadIdx.x & 63;
    int eg = l >> 4;
    int cl = l & 15;

    int start = offs[node];
    int cnt = deg[node];
    float invd = inv[node];

    float acc[8];
    #pragma unroll
    for (int j = 0; j < 8; ++j) acc[j] = 0.f;

    if (eg == 0) {
        float sl = invd * invd;
        uint4 v = *(const uint4*)&XWb[node * D + cl * 8];
        acc[0] += sl * bflo(v.x); acc[1] += sl * bfhi(v.x);
        acc[2] += sl * bflo(v.y); acc[3] += sl * bfhi(v.y);
        acc[4] += sl * bflo(v.z); acc[5] += sl * bfhi(v.z);
        acc[6] += sl * bflo(v.w); acc[7] += sl * bfhi(v.w);
    }

    for (int e = eg; e < cnt; e += 16) {
        int s[4];
        #pragma unroll
        for (int u = 0; u < 4; ++u) {
            int ee = e + u * 4;
            s[u] = (ee < cnt) ? (int)csr[start + ee] : -1;
        }
        uint4 v[4];
        float nn[4];
        #pragma unroll
        for (int u = 0; u < 4; ++u) {
            int si = (s[u] >= 0) ? s[u] : s[0];
            v[u] = *(const uint4*)&XWb[si * D + cl * 8];
            nn[u] = (s[u] >= 0) ? invd * inv[si] : 0.f;
        }
        #pragma unroll
        for (int u = 0; u < 4; ++u) {
            float n = nn[u];
            acc[0] += n * bflo(v[u].x); acc[1] += n * bfhi(v[u].x);
            acc[2] += n * bflo(v[u].y); acc[3] += n * bfhi(v[u].y);
            acc[4] += n * bflo(v[u].z); acc[5] += n * bfhi(v[u].z);
            acc[6] += n * bflo(v[u].w); acc[7] += n * bfhi(v[u].w);
        }
    }

    #pragma unroll
    for (int j = 0; j < 8; ++j) {
        acc[j] += __shfl_xor(acc[j], 16, 64);
        acc[j] += __shfl_xor(acc[j], 32, 64);
    }

    if (l < 16) {
        float4 v0 = make_float4(acc[0], acc[1], acc[2], acc[3]);
        float4 v1 = make_float4(acc[4], acc[5], acc[6], acc[7]);
        *(float4*)&out[node * D + cl * 8] = v0;
        *(float4*)&out[node * D + cl * 8 + 4] = v1;
    }
}

extern "C" void kernel_launch(void* const* d_in, const int* in_sizes, int n_in,
                              void* d_out, int out_size, void* d_ws, size_t ws_size,
                              hipStream_t stream) {
    const float* X = (const float*)d_in[0];
    const float* W = (const float*)d_in[1];
    const int* esrc = (const int*)d_in[2];
    const int* edst = (const int*)d_in[3];
    float* out = (float*)d_out;

    char* ws = (char*)d_ws;
    int* flag = (int*)(ws + OFF_FLAG);
    int* part = (int*)(ws + OFF_PART);
    int* deg = (int*)(ws + OFF_DEG);
    int* offs = (int*)(ws + OFF_OFFS);
    float* inv = (float*)(ws + OFF_INV);
    unsigned short* Wt = (unsigned short*)(ws + OFF_WT);
    unsigned short* H = (unsigned short*)(ws + OFF_H);
    unsigned short* br = (unsigned short*)(ws + OFF_BR);
    unsigned short* csr = (unsigned short*)(ws + OFF_CSR);
    unsigned short* XWb = (unsigned short*)(ws + OFF_XWB);

    k_init<<<65, 256, 0, stream>>>(flag, W, Wt);
    k_hist<<<NTILE, 256, 0, stream>>>(edst, H);
    k_gemm<<<NB_GEMM, 256, 0, stream>>>(X, Wt, XWb);
    k_base<<<(N_NODES + 255) / 256, 256, 0, stream>>>(H, br, deg);
    k_scan<<<SCAN_NB, SCAN_B, 0, stream>>>(deg, part, flag, offs, inv);
    k_csr<<<NTILE, 256, 0, stream>>>(esrc, edst, offs, br, csr);
    k_agg<<<(N_NODES + 3) / 4, 256, 0, stream>>>(XWb, csr, offs, deg, inv, out);
}

// Round 8
// 115.371 us; speedup vs baseline: 1.0582x; 1.0582x over previous
//
#include <hip/hip_runtime.h>

#define N_NODES 50000
#define N_EDGES 800000
#define D 128
#define NC 8                      // degree-counter replication factor

typedef __attribute__((ext_vector_type(8))) short bf16x8;
typedef __attribute__((ext_vector_type(4))) float f32x4;

// ---------------- workspace layout (bytes) ----------------
static const size_t OFF_FLAG = 0;          // int[49] lookback flags (zeroed)
static const size_t OFF_PART = 256;        // int[49] block totals (flag-gated)
static const size_t OFF_DEG8 = 512;        // int[NC][50000] replicated counters (zeroed)
static const size_t OFF_DEG  = 1600512;    // int[50000] total degree
static const size_t OFF_OFFS = 1800512;    // int[50000]
static const size_t OFF_INV  = 2000512;    // float[50000]
static const size_t OFF_WT   = 2200512;    // ushort[128*128] bf16 W^T [n][k]
static const size_t OFF_SLOT = 2233344;    // ushort[800000] rank within (copy,node)
static const size_t OFF_BR8  = 3833344;    // ushort[NC][50000] per-copy base within node
static const size_t OFF_CSR  = 4633344;    // ushort[800000]
static const size_t OFF_XWB  = 6233408;    // ushort[50000*128] bf16
// total: 19,033,408 bytes
// zero region = [0, 1600512) = 100032 int4

#define SCAN_B 1024
#define SCAN_NB ((N_NODES + SCAN_B - 1) / SCAN_B)   // 49
#define BM 64
#define NB_GEMM ((N_NODES + BM - 1) / BM)           // 782

__device__ __forceinline__ unsigned short f2bf(float f) {
    unsigned int u = __float_as_uint(f);
    unsigned int r = (u + 0x7fffu + ((u >> 16) & 1u)) >> 16;   // RNE
    return (unsigned short)r;
}
__device__ __forceinline__ float bflo(unsigned int u) { return __uint_as_float(u << 16); }
__device__ __forceinline__ float bfhi(unsigned int u) { return __uint_as_float(u & 0xffff0000u); }

// ---- init: zero flags+deg8, convert Wt[n][k] = bf16(W[k][n]) ----
__global__ void k_init(int4* __restrict__ zreg, const float* __restrict__ W,
                       unsigned short* __restrict__ Wt) {
    int bid = blockIdx.x, t = threadIdx.x;
    if (bid < 391) {
        int i = bid * 256 + t;
        if (i < 100032) zreg[i] = make_int4(0, 0, 0, 0);
    } else {
        int idx = (bid - 391) * 256 + t;   // 0..16383
        int n = idx >> 7, k = idx & 127;
        Wt[n * D + k] = f2bf(W[k * D + n]);
    }
}

// ---- degree+slot: replicated counters (copy = blockIdx&7), 256 edges/block ----
__global__ __launch_bounds__(256) void k_deg(const int* __restrict__ dst,
                                             int* __restrict__ deg8,
                                             unsigned short* __restrict__ slot) {
    int bid = blockIdx.x;
    int e = bid * 256 + threadIdx.x;       // grid exactly covers N_EDGES
    int d = dst[e];
    int p = atomicAdd(&deg8[(bid & (NC - 1)) * N_NODES + d], 1);
    slot[e] = (unsigned short)p;
}

// ---- fused base+scan: sum copies -> br8/deg/inv, then lookback scan -> offs ----
__global__ __launch_bounds__(1024) void k_scan(const int* __restrict__ deg8,
                                               unsigned short* __restrict__ br8,
                                               int* __restrict__ deg,
                                               int* __restrict__ part,
                                               int* __restrict__ flag,
                                               int* __restrict__ offs,
                                               float* __restrict__ inv) {
    int b = blockIdx.x;
    int t = threadIdx.x;
    int i = b * SCAN_B + t;
    int v = 0;
    if (i < N_NODES) {
        int run = 0;
        #pragma unroll
        for (int g = 0; g < NC; ++g) {
            int c = deg8[g * N_NODES + i];          // coalesced per copy
            br8[g * N_NODES + i] = (unsigned short)run;
            run += c;
        }
        v = run;
        deg[i] = v;
        inv[i] = rsqrtf((float)v + 1.0f);
    }
    int s = v;
    #pragma unroll
    for (int d = 1; d < 64; d <<= 1) {
        int u = __shfl_up(s, d, 64);
        if ((t & 63) >= d) s += u;
    }
    __shared__ int wsum[16];
    __shared__ int s_prefix;
    if ((t & 63) == 63) wsum[t >> 6] = s;
    __syncthreads();
    if (t < 64) {
        int val = (t < 16) ? wsum[t] : 0;
        int sc = val;
        #pragma unroll
        for (int d = 1; d < 16; d <<= 1) {
            int u = __shfl_up(sc, d, 64);
            if (t >= d) sc += u;
        }
        if (t < 16) wsum[t] = sc - val;     // exclusive over waves
        int total = __shfl(sc, 15, 64);     // block total
        if (t == 0) {
            part[b] = total;
            __threadfence();
            atomicExch(&flag[b], 1);
        }
        int pv = 0;
        if (t < b) {
            while (atomicAdd(&flag[t], 0) == 0) { }
        }
        __threadfence();
        if (t < b) pv = atomicAdd(&part[t], 0);
        #pragma unroll
        for (int off = 32; off >= 1; off >>= 1) pv += __shfl_down(pv, off, 64);
        if (t == 0) s_prefix = pv;
    }
    __syncthreads();
    if (i < N_NODES) {
        offs[i] = s - v + wsum[t >> 6] + s_prefix;
    }
}

// ---- atomic-free CSR fill: 2-byte scatter ----
__global__ __launch_bounds__(256) void k_fill(const int* __restrict__ src,
                                              const int* __restrict__ dst,
                                              const int* __restrict__ offs,
                                              const unsigned short* __restrict__ br8,
                                              const unsigned short* __restrict__ slot,
                                              unsigned short* __restrict__ csr) {
    int e = blockIdx.x * 256 + threadIdx.x;   // grid exactly covers N_EDGES
    int d = dst[e];
    int g = (e >> 8) & (NC - 1);
    csr[offs[d] + (int)br8[g * N_NODES + d] + (int)slot[e]] = (unsigned short)src[e];
}

// ---- pure MFMA GEMM: XW(bf16) = X @ W, XOR-swizzled LDS ----
__global__ __launch_bounds__(256) void k_gemm(const float* __restrict__ X,
                                              const unsigned short* __restrict__ Wt,
                                              unsigned short* __restrict__ XWb) {
    __shared__ unsigned short sA[BM * D];    // 16KB swizzled [row][k]
    __shared__ unsigned short sB[D * D];     // 32KB swizzled [n][k]
    int t = threadIdx.x;
    int r0 = blockIdx.x * BM;

    #pragma unroll
    for (int p = 0; p < 8; ++p) {
        int e = p * 2048 + t * 8;
        int n = e >> 7, k = e & 127;
        uint4 v = *(const uint4*)&Wt[e];
        int idx = n * D + (((k >> 3) ^ (n & 7)) << 3);
        *(uint4*)&sB[idx] = v;
    }
    #pragma unroll
    for (int p = 0; p < 8; ++p) {
        int e = p * 1024 + t * 4;
        int r = e >> 7, c = e & 127;
        int row = r0 + r;
        float4 xv = make_float4(0.f, 0.f, 0.f, 0.f);
        if (row < N_NODES) xv = *(const float4*)&X[row * D + c];
        ushort4 bv;
        bv.x = f2bf(xv.x); bv.y = f2bf(xv.y); bv.z = f2bf(xv.z); bv.w = f2bf(xv.w);
        int idx = r * D + (((c >> 3) ^ (r & 7)) << 3) + (c & 7);
        *(ushort4*)&sA[idx] = bv;
    }
    __syncthreads();

    int w = t >> 6, l = t & 63;
    int arow = w * 16 + (l & 15);
    f32x4 acc[8];
    #pragma unroll
    for (int i = 0; i < 8; ++i) acc[i] = (f32x4){0.f, 0.f, 0.f, 0.f};

    #pragma unroll
    for (int kk = 0; kk < 4; ++kk) {
        int g = kk * 4 + (l >> 4);
        bf16x8 a = *(bf16x8*)&sA[arow * D + ((g ^ (arow & 7)) << 3)];
        #pragma unroll
        for (int nt = 0; nt < 8; ++nt) {
            int nrow = nt * 16 + (l & 15);
            bf16x8 b = *(bf16x8*)&sB[nrow * D + ((g ^ (nrow & 7)) << 3)];
            acc[nt] = __builtin_amdgcn_mfma_f32_16x16x32_bf16(a, b, acc[nt], 0, 0, 0);
        }
    }

    #pragma unroll
    for (int nt = 0; nt < 8; ++nt) {
        #pragma unroll
        for (int r = 0; r < 4; ++r) {
            int m = r0 + w * 16 + (l >> 4) * 4 + r;
            if (m < N_NODES) XWb[m * D + nt * 16 + (l & 15)] = f2bf(acc[nt][r]);
        }
    }
}

// ---- aggregate (bf16 gather, f32 out), 4-deep gather pipeline ----
__global__ __launch_bounds__(256) void k_agg(const unsigned short* __restrict__ XWb,
                                             const unsigned short* __restrict__ csr,
                                             const int* __restrict__ offs,
                                             const int* __restrict__ deg,
                                             const float* __restrict__ inv,
                                             float* __restrict__ out) {
    int node = blockIdx.x * 4 + (threadIdx.x >> 6);
    if (node >= N_NODES) return;
    int l = threadIdx.x & 63;
    int eg = l >> 4;
    int cl = l & 15;

    int start = offs[node];
    int cnt = deg[node];
    float invd = inv[node];

    float acc[8];
    #pragma unroll
    for (int j = 0; j < 8; ++j) acc[j] = 0.f;

    if (eg == 0) {
        float sl = invd * invd;
        uint4 v = *(const uint4*)&XWb[node * D + cl * 8];
        acc[0] += sl * bflo(v.x); acc[1] += sl * bfhi(v.x);
        acc[2] += sl * bflo(v.y); acc[3] += sl * bfhi(v.y);
        acc[4] += sl * bflo(v.z); acc[5] += sl * bfhi(v.z);
        acc[6] += sl * bflo(v.w); acc[7] += sl * bfhi(v.w);
    }

    for (int e = eg; e < cnt; e += 16) {
        int s[4];
        #pragma unroll
        for (int u = 0; u < 4; ++u) {
            int ee = e + u * 4;
            s[u] = (ee < cnt) ? (int)csr[start + ee] : -1;
        }
        uint4 v[4];
        float nn[4];
        #pragma unroll
        for (int u = 0; u < 4; ++u) {
            int si = (s[u] >= 0) ? s[u] : s[0];
            v[u] = *(const uint4*)&XWb[si * D + cl * 8];
            nn[u] = (s[u] >= 0) ? invd * inv[si] : 0.f;
        }
        #pragma unroll
        for (int u = 0; u < 4; ++u) {
            float n = nn[u];
            acc[0] += n * bflo(v[u].x); acc[1] += n * bfhi(v[u].x);
            acc[2] += n * bflo(v[u].y); acc[3] += n * bfhi(v[u].y);
            acc[4] += n * bflo(v[u].z); acc[5] += n * bfhi(v[u].z);
            acc[6] += n * bflo(v[u].w); acc[7] += n * bfhi(v[u].w);
        }
    }

    #pragma unroll
    for (int j = 0; j < 8; ++j) {
        acc[j] += __shfl_xor(acc[j], 16, 64);
        acc[j] += __shfl_xor(acc[j], 32, 64);
    }

    if (l < 16) {
        float4 v0 = make_float4(acc[0], acc[1], acc[2], acc[3]);
        float4 v1 = make_float4(acc[4], acc[5], acc[6], acc[7]);
        *(float4*)&out[node * D + cl * 8] = v0;
        *(float4*)&out[node * D + cl * 8 + 4] = v1;
    }
}

extern "C" void kernel_launch(void* const* d_in, const int* in_sizes, int n_in,
                              void* d_out, int out_size, void* d_ws, size_t ws_size,
                              hipStream_t stream) {
    const float* X = (const float*)d_in[0];
    const float* W = (const float*)d_in[1];
    const int* esrc = (const int*)d_in[2];
    const int* edst = (const int*)d_in[3];
    float* out = (float*)d_out;

    char* ws = (char*)d_ws;
    int* flag = (int*)(ws + OFF_FLAG);
    int* part = (int*)(ws + OFF_PART);
    int* deg8 = (int*)(ws + OFF_DEG8);
    int* deg = (int*)(ws + OFF_DEG);
    int* offs = (int*)(ws + OFF_OFFS);
    float* inv = (float*)(ws + OFF_INV);
    unsigned short* Wt = (unsigned short*)(ws + OFF_WT);
    unsigned short* slot = (unsigned short*)(ws + OFF_SLOT);
    unsigned short* br8 = (unsigned short*)(ws + OFF_BR8);
    unsigned short* csr = (unsigned short*)(ws + OFF_CSR);
    unsigned short* XWb = (unsigned short*)(ws + OFF_XWB);

    k_init<<<455, 256, 0, stream>>>((int4*)ws, W, Wt);
    k_deg<<<N_EDGES / 256, 256, 0, stream>>>(edst, deg8, slot);
    k_gemm<<<NB_GEMM, 256, 0, stream>>>(X, Wt, XWb);
    k_scan<<<SCAN_NB, SCAN_B, 0, stream>>>(deg8, br8, deg, part, flag, offs, inv);
    k_fill<<<N_EDGES / 256, 256, 0, stream>>>(esrc, edst, offs, br8, slot, csr);
    k_agg<<<(N_NODES + 3) / 4, 256, 0, stream>>>(XWb, csr, offs, deg, inv, out);
}

// Round 9
// 114.117 us; speedup vs baseline: 1.0698x; 1.0110x over previous
//
#include <hip/hip_runtime.h>

#define N_NODES 50000
#define N_EDGES 800000
#define D 128
#define NC 8                      // one degree-counter copy per XCD

typedef __attribute__((ext_vector_type(8))) short bf16x8;
typedef __attribute__((ext_vector_type(4))) float f32x4;

// ---------------- workspace layout (bytes) ----------------
static const size_t OFF_FLAG = 0;          // int[49] lookback flags (zeroed)
static const size_t OFF_PART = 256;        // int[49] block totals (flag-gated)
static const size_t OFF_DEG8 = 512;        // int[NC][50000] per-XCD counters (zeroed)
static const size_t OFF_DEG  = 1600512;    // int[50000] total degree
static const size_t OFF_OFFS = 1800512;    // int[50000]
static const size_t OFF_INV  = 2000512;    // float[50000]
static const size_t OFF_WT   = 2200512;    // ushort[128*128] bf16 W^T [n][k]
static const size_t OFF_SLOT = 2233344;    // ushort[800000]  (xcd<<13 | rank)
static const size_t OFF_BR8  = 3833344;    // ushort[NC][50000] per-copy base within node
static const size_t OFF_CSR  = 4633344;    // ushort[800000]
static const size_t OFF_XWB  = 6233408;    // ushort[50000*128] bf16
// total: 19,033,408 bytes
// zero region = [0, 1600512) = 100032 int4

#define SCAN_B 1024
#define SCAN_NB ((N_NODES + SCAN_B - 1) / SCAN_B)   // 49
#define BM 64
#define NB_GEMM ((N_NODES + BM - 1) / BM)           // 782

__device__ __forceinline__ unsigned short f2bf(float f) {
    unsigned int u = __float_as_uint(f);
    unsigned int r = (u + 0x7fffu + ((u >> 16) & 1u)) >> 16;   // RNE
    return (unsigned short)r;
}
__device__ __forceinline__ float bflo(unsigned int u) { return __uint_as_float(u << 16); }
__device__ __forceinline__ float bfhi(unsigned int u) { return __uint_as_float(u & 0xffff0000u); }

// ---- init: zero flags+deg8, convert Wt[n][k] = bf16(W[k][n]) ----
__global__ void k_init(int4* __restrict__ zreg, const float* __restrict__ W,
                       unsigned short* __restrict__ Wt) {
    int bid = blockIdx.x, t = threadIdx.x;
    if (bid < 391) {
        int i = bid * 256 + t;
        if (i < 100032) zreg[i] = make_int4(0, 0, 0, 0);
    } else {
        int idx = (bid - 391) * 256 + t;   // 0..16383
        int n = idx >> 7, k = idx & 127;
        Wt[n * D + k] = f2bf(W[k * D + n]);
    }
}

// ---- degree+slot: XCD-local L2 atomics (workgroup scope, copy = hw XCC id) ----
__global__ __launch_bounds__(256) void k_deg(const int* __restrict__ dst,
                                             int* __restrict__ deg8,
                                             unsigned short* __restrict__ slot) {
    unsigned int xcc;
    asm("s_getreg_b32 %0, hwreg(HW_REG_XCC_ID, 0, 32)" : "=s"(xcc));
    xcc &= (NC - 1);
    int e = blockIdx.x * 256 + threadIdx.x;       // grid exactly covers N_EDGES
    int d = dst[e];
    int p = __hip_atomic_fetch_add(&deg8[xcc * N_NODES + d], 1,
                                   __ATOMIC_RELAXED, __HIP_MEMORY_SCOPE_WORKGROUP);
    slot[e] = (unsigned short)((xcc << 13) | (unsigned)p);
}

// ---- fused base+scan: sum copies -> br8/deg/inv, then lookback scan -> offs ----
__global__ __launch_bounds__(1024) void k_scan(const int* __restrict__ deg8,
                                               unsigned short* __restrict__ br8,
                                               int* __restrict__ deg,
                                               int* __restrict__ part,
                                               int* __restrict__ flag,
                                               int* __restrict__ offs,
                                               float* __restrict__ inv) {
    int b = blockIdx.x;
    int t = threadIdx.x;
    int i = b * SCAN_B + t;
    int v = 0;
    if (i < N_NODES) {
        int run = 0;
        #pragma unroll
        for (int g = 0; g < NC; ++g) {
            int c = deg8[g * N_NODES + i];          // coalesced per copy
            br8[g * N_NODES + i] = (unsigned short)run;
            run += c;
        }
        v = run;
        deg[i] = v;
        inv[i] = rsqrtf((float)v + 1.0f);
    }
    int s = v;
    #pragma unroll
    for (int d = 1; d < 64; d <<= 1) {
        int u = __shfl_up(s, d, 64);
        if ((t & 63) >= d) s += u;
    }
    __shared__ int wsum[16];
    __shared__ int s_prefix;
    if ((t & 63) == 63) wsum[t >> 6] = s;
    __syncthreads();
    if (t < 64) {
        int val = (t < 16) ? wsum[t] : 0;
        int sc = val;
        #pragma unroll
        for (int d = 1; d < 16; d <<= 1) {
            int u = __shfl_up(sc, d, 64);
            if (t >= d) sc += u;
        }
        if (t < 16) wsum[t] = sc - val;     // exclusive over waves
        int total = __shfl(sc, 15, 64);     // block total
        if (t == 0) {
            part[b] = total;
            __threadfence();
            atomicExch(&flag[b], 1);        // device scope (cross-XCD) — only 49 of these
        }
        int pv = 0;
        if (t < b) {
            while (atomicAdd(&flag[t], 0) == 0) { }
        }
        __threadfence();
        if (t < b) pv = atomicAdd(&part[t], 0);
        #pragma unroll
        for (int off = 32; off >= 1; off >>= 1) pv += __shfl_down(pv, off, 64);
        if (t == 0) s_prefix = pv;
    }
    __syncthreads();
    if (i < N_NODES) {
        offs[i] = s - v + wsum[t >> 6] + s_prefix;
    }
}

// ---- atomic-free CSR fill: 2-byte scatter ----
__global__ __launch_bounds__(256) void k_fill(const int* __restrict__ src,
                                              const int* __restrict__ dst,
                                              const int* __restrict__ offs,
                                              const unsigned short* __restrict__ br8,
                                              const unsigned short* __restrict__ slot,
                                              unsigned short* __restrict__ csr) {
    int e = blockIdx.x * 256 + threadIdx.x;   // grid exactly covers N_EDGES
    int d = dst[e];
    unsigned int sl = slot[e];
    int g = sl >> 13;
    int rank = sl & 0x1FFF;
    csr[offs[d] + (int)br8[g * N_NODES + d] + rank] = (unsigned short)src[e];
}

// ---- pure MFMA GEMM: XW(bf16) = X @ W, XOR-swizzled LDS ----
__global__ __launch_bounds__(256) void k_gemm(const float* __restrict__ X,
                                              const unsigned short* __restrict__ Wt,
                                              unsigned short* __restrict__ XWb) {
    __shared__ unsigned short sA[BM * D];    // 16KB swizzled [row][k]
    __shared__ unsigned short sB[D * D];     // 32KB swizzled [n][k]
    int t = threadIdx.x;
    int r0 = blockIdx.x * BM;

    #pragma unroll
    for (int p = 0; p < 8; ++p) {
        int e = p * 2048 + t * 8;
        int n = e >> 7, k = e & 127;
        uint4 v = *(const uint4*)&Wt[e];
        int idx = n * D + (((k >> 3) ^ (n & 7)) << 3);
        *(uint4*)&sB[idx] = v;
    }
    #pragma unroll
    for (int p = 0; p < 8; ++p) {
        int e = p * 1024 + t * 4;
        int r = e >> 7, c = e & 127;
        int row = r0 + r;
        float4 xv = make_float4(0.f, 0.f, 0.f, 0.f);
        if (row < N_NODES) xv = *(const float4*)&X[row * D + c];
        ushort4 bv;
        bv.x = f2bf(xv.x); bv.y = f2bf(xv.y); bv.z = f2bf(xv.z); bv.w = f2bf(xv.w);
        int idx = r * D + (((c >> 3) ^ (r & 7)) << 3) + (c & 7);
        *(ushort4*)&sA[idx] = bv;
    }
    __syncthreads();

    int w = t >> 6, l = t & 63;
    int arow = w * 16 + (l & 15);
    f32x4 acc[8];
    #pragma unroll
    for (int i = 0; i < 8; ++i) acc[i] = (f32x4){0.f, 0.f, 0.f, 0.f};

    #pragma unroll
    for (int kk = 0; kk < 4; ++kk) {
        int g = kk * 4 + (l >> 4);
        bf16x8 a = *(bf16x8*)&sA[arow * D + ((g ^ (arow & 7)) << 3)];
        #pragma unroll
        for (int nt = 0; nt < 8; ++nt) {
            int nrow = nt * 16 + (l & 15);
            bf16x8 b = *(bf16x8*)&sB[nrow * D + ((g ^ (nrow & 7)) << 3)];
            acc[nt] = __builtin_amdgcn_mfma_f32_16x16x32_bf16(a, b, acc[nt], 0, 0, 0);
        }
    }

    #pragma unroll
    for (int nt = 0; nt < 8; ++nt) {
        #pragma unroll
        for (int r = 0; r < 4; ++r) {
            int m = r0 + w * 16 + (l >> 4) * 4 + r;
            if (m < N_NODES) XWb[m * D + nt * 16 + (l & 15)] = f2bf(acc[nt][r]);
        }
    }
}

// ---- aggregate (bf16 gather, f32 out), 4-deep gather pipeline ----
__global__ __launch_bounds__(256) void k_agg(const unsigned short* __restrict__ XWb,
                                             const unsigned short* __restrict__ csr,
                                             const int* __restrict__ offs,
                                             const int* __restrict__ deg,
                                             const float* __restrict__ inv,
                                             float* __restrict__ out) {
    int node = blockIdx.x * 4 + (threadIdx.x >> 6);
    if (node >= N_NODES) return;
    int l = threadIdx.x & 63;
    int eg = l >> 4;
    int cl = l & 15;

    int start = offs[node];
    int cnt = deg[node];
    float invd = inv[node];

    float acc[8];
    #pragma unroll
    for (int j = 0; j < 8; ++j) acc[j] = 0.f;

    if (eg == 0) {
        float sl = invd * invd;
        uint4 v = *(const uint4*)&XWb[node * D + cl * 8];
        acc[0] += sl * bflo(v.x); acc[1] += sl * bfhi(v.x);
        acc[2] += sl * bflo(v.y); acc[3] += sl * bfhi(v.y);
        acc[4] += sl * bflo(v.z); acc[5] += sl * bfhi(v.z);
        acc[6] += sl * bflo(v.w); acc[7] += sl * bfhi(v.w);
    }

    for (int e = eg; e < cnt; e += 16) {
        int s[4];
        #pragma unroll
        for (int u = 0; u < 4; ++u) {
            int ee = e + u * 4;
            s[u] = (ee < cnt) ? (int)csr[start + ee] : -1;
        }
        uint4 v[4];
        float nn[4];
        #pragma unroll
        for (int u = 0; u < 4; ++u) {
            int si = (s[u] >= 0) ? s[u] : s[0];
            v[u] = *(const uint4*)&XWb[si * D + cl * 8];
            nn[u] = (s[u] >= 0) ? invd * inv[si] : 0.f;
        }
        #pragma unroll
        for (int u = 0; u < 4; ++u) {
            float n = nn[u];
            acc[0] += n * bflo(v[u].x); acc[1] += n * bfhi(v[u].x);
            acc[2] += n * bflo(v[u].y); acc[3] += n * bfhi(v[u].y);
            acc[4] += n * bflo(v[u].z); acc[5] += n * bfhi(v[u].z);
            acc[6] += n * bflo(v[u].w); acc[7] += n * bfhi(v[u].w);
        }
    }

    #pragma unroll
    for (int j = 0; j < 8; ++j) {
        acc[j] += __shfl_xor(acc[j], 16, 64);
        acc[j] += __shfl_xor(acc[j], 32, 64);
    }

    if (l < 16) {
        float4 v0 = make_float4(acc[0], acc[1], acc[2], acc[3]);
        float4 v1 = make_float4(acc[4], acc[5], acc[6], acc[7]);
        *(float4*)&out[node * D + cl * 8] = v0;
        *(float4*)&out[node * D + cl * 8 + 4] = v1;
    }
}

extern "C" void kernel_launch(void* const* d_in, const int* in_sizes, int n_in,
                              void* d_out, int out_size, void* d_ws, size_t ws_size,
                              hipStream_t stream) {
    const float* X = (const float*)d_in[0];
    const float* W = (const float*)d_in[1];
    const int* esrc = (const int*)d_in[2];
    const int* edst = (const int*)d_in[3];
    float* out = (float*)d_out;

    char* ws = (char*)d_ws;
    int* flag = (int*)(ws + OFF_FLAG);
    int* part = (int*)(ws + OFF_PART);
    int* deg8 = (int*)(ws + OFF_DEG8);
    int* deg = (int*)(ws + OFF_DEG);
    int* offs = (int*)(ws + OFF_OFFS);
    float* inv = (float*)(ws + OFF_INV);
    unsigned short* Wt = (unsigned short*)(ws + OFF_WT);
    unsigned short* slot = (unsigned short*)(ws + OFF_SLOT);
    unsigned short* br8 = (unsigned short*)(ws + OFF_BR8);
    unsigned short* csr = (unsigned short*)(ws + OFF_CSR);
    unsigned short* XWb = (unsigned short*)(ws + OFF_XWB);

    k_init<<<455, 256, 0, stream>>>((int4*)ws, W, Wt);
    k_deg<<<N_EDGES / 256, 256, 0, stream>>>(edst, deg8, slot);
    k_gemm<<<NB_GEMM, 256, 0, stream>>>(X, Wt, XWb);
    k_scan<<<SCAN_NB, SCAN_B, 0, stream>>>(deg8, br8, deg, part, flag, offs, inv);
    k_fill<<<N_EDGES / 256, 256, 0, stream>>>(esrc, edst, offs, br8, slot, csr);
    k_agg<<<(N_NODES + 3) / 4, 256, 0, stream>>>(XWb, csr, offs, deg, inv, out);
}

// Round 10
// 101.456 us; speedup vs baseline: 1.2033x; 1.1248x over previous
//
#include <hip/hip_runtime.h>

#define N_NODES 50000
#define N_EDGES 800000
#define D 128

#define NBLK 256                  // partition blocks
#define EPB (N_EDGES / NBLK)      // 3125 edges per block
#define NBKT 196                  // coarse buckets of 256 nodes

typedef __attribute__((ext_vector_type(8))) short bf16x8;
typedef __attribute__((ext_vector_type(4))) float f32x4;

// ---------------- workspace layout (bytes) ----------------
static const size_t OFF_FLAG = 0;          // int[196] lookback flags (zeroed)
static const size_t OFF_BASE = 1024;       // int[196] bucket base (edge index)
static const size_t OFF_TOT  = 2048;       // int[196] bucket edge count
static const size_t OFF_WT   = 3072;       // ushort[128*128] bf16 W^T [n][k]
static const size_t OFF_H    = 35840;      // int[196*256] per-(bucket,block) counts
static const size_t OFF_BB   = 236544;     // int[196*256] absolute scatter bases
static const size_t OFF_DEG  = 437248;     // int[50000]
static const size_t OFF_OFFS = 637952;     // int[50000]
static const size_t OFF_INV  = 838656;     // float[50000]
static const size_t OFF_REC  = 1039360;    // uint[800000] (src | dstLocal<<16)
static const size_t OFF_CSR  = 4239360;    // ushort[800000]
static const size_t OFF_XWB  = 5839360;    // ushort[50000*128] bf16
// total: 18,639,360 bytes

#define BM 64
#define NB_GEMM ((N_NODES + BM - 1) / BM)   // 782

__device__ __forceinline__ unsigned short f2bf(float f) {
    unsigned int u = __float_as_uint(f);
    unsigned int r = (u + 0x7fffu + ((u >> 16) & 1u)) >> 16;   // RNE
    return (unsigned short)r;
}
__device__ __forceinline__ float bflo(unsigned int u) { return __uint_as_float(u << 16); }
__device__ __forceinline__ float bfhi(unsigned int u) { return __uint_as_float(u & 0xffff0000u); }

// ---- init: zero lookback flags, convert Wt[n][k] = bf16(W[k][n]) ----
__global__ void k_init(int* __restrict__ flag, const float* __restrict__ W,
                       unsigned short* __restrict__ Wt) {
    int bid = blockIdx.x, t = threadIdx.x;
    if (bid == 0) {
        if (t < NBKT) flag[t] = 0;
    } else {
        int idx = (bid - 1) * 256 + t;   // 0..16383
        int n = idx >> 7, k = idx & 127;
        Wt[n * D + k] = f2bf(W[k * D + n]);
    }
}

// ---- pass A: per-block coarse histogram (LDS atomics only) ----
__global__ __launch_bounds__(512) void k_pA(const int* __restrict__ dst,
                                            int* __restrict__ H) {
    __shared__ unsigned int cnt[200];
    int b = blockIdx.x, t = threadIdx.x;
    if (t < 200) cnt[t] = 0;
    __syncthreads();
    int e0 = b * EPB;
    for (int i = t; i < EPB; i += 512)
        atomicAdd(&cnt[dst[e0 + i] >> 8], 1u);
    __syncthreads();
    if (t < NBKT) H[t * NBLK + b] = (int)cnt[t];
}

// ---- pass B: per-bucket scan over blocks + lookback over buckets ----
__global__ __launch_bounds__(256) void k_pB(const int* __restrict__ H,
                                            int* __restrict__ BB,
                                            int* __restrict__ TOT,
                                            int* __restrict__ flag,
                                            int* __restrict__ BASE) {
    int k = blockIdx.x, t = threadIdx.x;
    int w = t >> 6, l = t & 63;
    int v = H[k * NBLK + t];
    int s = v;
    #pragma unroll
    for (int d = 1; d < 64; d <<= 1) {
        int u = __shfl_up(s, d, 64);
        if (l >= d) s += u;
    }
    __shared__ int wtot[4], woff[4], red[4];
    __shared__ int s_base;
    if (l == 63) wtot[w] = s;
    __syncthreads();
    if (t == 0) {
        woff[0] = 0; woff[1] = wtot[0];
        woff[2] = wtot[0] + wtot[1]; woff[3] = wtot[0] + wtot[1] + wtot[2];
    }
    __syncthreads();
    int excl = s - v + woff[w];
    int T = woff[3] + wtot[3];
    if (t == 0) {
        TOT[k] = T;
        __threadfence();
        atomicExch(&flag[k], 1);
    }
    int pv = 0;
    if (t < k) {
        while (atomicAdd(&flag[t], 0) == 0) { }
    }
    __threadfence();
    if (t < k) pv = atomicAdd(&TOT[t], 0);
    #pragma unroll
    for (int off = 32; off >= 1; off >>= 1) pv += __shfl_down(pv, off, 64);
    if (l == 0) red[w] = pv;
    __syncthreads();
    if (t == 0) {
        s_base = red[0] + red[1] + red[2] + red[3];
        BASE[k] = s_base;
    }
    __syncthreads();
    BB[k * NBLK + t] = s_base + excl;
}

// ---- pass C: rank-capturing re-histogram + record scatter (bucket-grouped) ----
__global__ __launch_bounds__(512) void k_pC(const int* __restrict__ src,
                                            const int* __restrict__ dst,
                                            const int* __restrict__ BB,
                                            unsigned int* __restrict__ rec) {
    __shared__ unsigned int cnt[200];
    __shared__ int myBB[NBKT];
    int b = blockIdx.x, t = threadIdx.x;
    if (t < 200) cnt[t] = 0;
    if (t < NBKT) myBB[t] = BB[t * NBLK + b];
    __syncthreads();
    int e0 = b * EPB;
    for (int i = t; i < EPB; i += 512) {
        int e = e0 + i;
        int d = dst[e];
        int k = d >> 8;
        unsigned int r = atomicAdd(&cnt[k], 1u);
        rec[myBB[k] + (int)r] = (unsigned int)src[e] | ((unsigned int)(d & 255) << 16);
    }
}

// ---- pass D: exact-dst sort within bucket -> deg/inv/offs + csr ----
__global__ __launch_bounds__(256) void k_pD(const unsigned int* __restrict__ rec,
                                            const int* __restrict__ BASE,
                                            const int* __restrict__ TOT,
                                            int* __restrict__ deg,
                                            int* __restrict__ offs,
                                            float* __restrict__ inv,
                                            unsigned short* __restrict__ csr) {
    __shared__ unsigned int cnt[256];
    __shared__ int off_l[256];
    __shared__ int wtot[4], woff[4];
    int k = blockIdx.x, t = threadIdx.x;
    int w = t >> 6, l = t & 63;
    int base = BASE[k], tot = TOT[k];

    cnt[t] = 0;
    __syncthreads();
    for (int i = t; i < tot; i += 256)
        atomicAdd(&cnt[rec[base + i] >> 16], 1u);
    __syncthreads();

    int v = (int)cnt[t];
    int s = v;
    #pragma unroll
    for (int d = 1; d < 64; d <<= 1) {
        int u = __shfl_up(s, d, 64);
        if (l >= d) s += u;
    }
    if (l == 63) wtot[w] = s;
    __syncthreads();
    if (t == 0) {
        woff[0] = 0; woff[1] = wtot[0];
        woff[2] = wtot[0] + wtot[1]; woff[3] = wtot[0] + wtot[1] + wtot[2];
    }
    __syncthreads();
    int excl = s - v + woff[w];
    off_l[t] = excl;
    int node = k * 256 + t;
    if (node < N_NODES) {
        deg[node] = v;
        inv[node] = rsqrtf((float)v + 1.0f);
        offs[node] = base + excl;
    }
    __syncthreads();
    cnt[t] = 0;
    __syncthreads();
    for (int i = t; i < tot; i += 256) {
        unsigned int rc = rec[base + i];
        int dl = rc >> 16;
        unsigned int r = atomicAdd(&cnt[dl], 1u);
        csr[base + off_l[dl] + (int)r] = (unsigned short)(rc & 0xFFFFu);
    }
}

// ---- pure MFMA GEMM: XW(bf16) = X @ W, XOR-swizzled LDS ----
__global__ __launch_bounds__(256) void k_gemm(const float* __restrict__ X,
                                              const unsigned short* __restrict__ Wt,
                                              unsigned short* __restrict__ XWb) {
    __shared__ unsigned short sA[BM * D];    // 16KB swizzled [row][k]
    __shared__ unsigned short sB[D * D];     // 32KB swizzled [n][k]
    int t = threadIdx.x;
    int r0 = blockIdx.x * BM;

    #pragma unroll
    for (int p = 0; p < 8; ++p) {
        int e = p * 2048 + t * 8;
        int n = e >> 7, k = e & 127;
        uint4 v = *(const uint4*)&Wt[e];
        int idx = n * D + (((k >> 3) ^ (n & 7)) << 3);
        *(uint4*)&sB[idx] = v;
    }
    #pragma unroll
    for (int p = 0; p < 8; ++p) {
        int e = p * 1024 + t * 4;
        int r = e >> 7, c = e & 127;
        int row = r0 + r;
        float4 xv = make_float4(0.f, 0.f, 0.f, 0.f);
        if (row < N_NODES) xv = *(const float4*)&X[row * D + c];
        ushort4 bv;
        bv.x = f2bf(xv.x); bv.y = f2bf(xv.y); bv.z = f2bf(xv.z); bv.w = f2bf(xv.w);
        int idx = r * D + (((c >> 3) ^ (r & 7)) << 3) + (c & 7);
        *(ushort4*)&sA[idx] = bv;
    }
    __syncthreads();

    int w = t >> 6, l = t & 63;
    int arow = w * 16 + (l & 15);
    f32x4 acc[8];
    #pragma unroll
    for (int i = 0; i < 8; ++i) acc[i] = (f32x4){0.f, 0.f, 0.f, 0.f};

    #pragma unroll
    for (int kk = 0; kk < 4; ++kk) {
        int g = kk * 4 + (l >> 4);
        bf16x8 a = *(bf16x8*)&sA[arow * D + ((g ^ (arow & 7)) << 3)];
        #pragma unroll
        for (int nt = 0; nt < 8; ++nt) {
            int nrow = nt * 16 + (l & 15);
            bf16x8 b = *(bf16x8*)&sB[nrow * D + ((g ^ (nrow & 7)) << 3)];
            acc[nt] = __builtin_amdgcn_mfma_f32_16x16x32_bf16(a, b, acc[nt], 0, 0, 0);
        }
    }

    #pragma unroll
    for (int nt = 0; nt < 8; ++nt) {
        #pragma unroll
        for (int r = 0; r < 4; ++r) {
            int m = r0 + w * 16 + (l >> 4) * 4 + r;
            if (m < N_NODES) XWb[m * D + nt * 16 + (l & 15)] = f2bf(acc[nt][r]);
        }
    }
}

// ---- aggregate (bf16 gather, f32 out), 4-deep gather pipeline ----
__global__ __launch_bounds__(256) void k_agg(const unsigned short* __restrict__ XWb,
                                             const unsigned short* __restrict__ csr,
                                             const int* __restrict__ offs,
                                             const int* __restrict__ deg,
                                             const float* __restrict__ inv,
                                             float* __restrict__ out) {
    int node = blockIdx.x * 4 + (threadIdx.x >> 6);
    if (node >= N_NODES) return;
    int l = threadIdx.x & 63;
    int eg = l >> 4;
    int cl = l & 15;

    int start = offs[node];
    int cnt = deg[node];
    float invd = inv[node];

    float acc[8];
    #pragma unroll
    for (int j = 0; j < 8; ++j) acc[j] = 0.f;

    if (eg == 0) {
        float sl = invd * invd;
        uint4 v = *(const uint4*)&XWb[node * D + cl * 8];
        acc[0] += sl * bflo(v.x); acc[1] += sl * bfhi(v.x);
        acc[2] += sl * bflo(v.y); acc[3] += sl * bfhi(v.y);
        acc[4] += sl * bflo(v.z); acc[5] += sl * bfhi(v.z);
        acc[6] += sl * bflo(v.w); acc[7] += sl * bfhi(v.w);
    }

    for (int e = eg; e < cnt; e += 16) {
        int s[4];
        #pragma unroll
        for (int u = 0; u < 4; ++u) {
            int ee = e + u * 4;
            s[u] = (ee < cnt) ? (int)csr[start + ee] : -1;
        }
        uint4 v[4];
        float nn[4];
        #pragma unroll
        for (int u = 0; u < 4; ++u) {
            int si = (s[u] >= 0) ? s[u] : s[0];
            v[u] = *(const uint4*)&XWb[si * D + cl * 8];
            nn[u] = (s[u] >= 0) ? invd * inv[si] : 0.f;
        }
        #pragma unroll
        for (int u = 0; u < 4; ++u) {
            float n = nn[u];
            acc[0] += n * bflo(v[u].x); acc[1] += n * bfhi(v[u].x);
            acc[2] += n * bflo(v[u].y); acc[3] += n * bfhi(v[u].y);
            acc[4] += n * bflo(v[u].z); acc[5] += n * bfhi(v[u].z);
            acc[6] += n * bflo(v[u].w); acc[7] += n * bfhi(v[u].w);
        }
    }

    #pragma unroll
    for (int j = 0; j < 8; ++j) {
        acc[j] += __shfl_xor(acc[j], 16, 64);
        acc[j] += __shfl_xor(acc[j], 32, 64);
    }

    if (l < 16) {
        float4 v0 = make_float4(acc[0], acc[1], acc[2], acc[3]);
        float4 v1 = make_float4(acc[4], acc[5], acc[6], acc[7]);
        *(float4*)&out[node * D + cl * 8] = v0;
        *(float4*)&out[node * D + cl * 8 + 4] = v1;
    }
}

extern "C" void kernel_launch(void* const* d_in, const int* in_sizes, int n_in,
                              void* d_out, int out_size, void* d_ws, size_t ws_size,
                              hipStream_t stream) {
    const float* X = (const float*)d_in[0];
    const float* W = (const float*)d_in[1];
    const int* esrc = (const int*)d_in[2];
    const int* edst = (const int*)d_in[3];
    float* out = (float*)d_out;

    char* ws = (char*)d_ws;
    int* flag = (int*)(ws + OFF_FLAG);
    int* BASE = (int*)(ws + OFF_BASE);
    int* TOT = (int*)(ws + OFF_TOT);
    unsigned short* Wt = (unsigned short*)(ws + OFF_WT);
    int* H = (int*)(ws + OFF_H);
    int* BB = (int*)(ws + OFF_BB);
    int* deg = (int*)(ws + OFF_DEG);
    int* offs = (int*)(ws + OFF_OFFS);
    float* inv = (float*)(ws + OFF_INV);
    unsigned int* rec = (unsigned int*)(ws + OFF_REC);
    unsigned short* csr = (unsigned short*)(ws + OFF_CSR);
    unsigned short* XWb = (unsigned short*)(ws + OFF_XWB);

    k_init<<<65, 256, 0, stream>>>(flag, W, Wt);
    k_pA<<<NBLK, 512, 0, stream>>>(edst, H);
    k_pB<<<NBKT, 256, 0, stream>>>(H, BB, TOT, flag, BASE);
    k_pC<<<NBLK, 512, 0, stream>>>(esrc, edst, BB, rec);
    k_pD<<<NBKT, 256, 0, stream>>>(rec, BASE, TOT, deg, offs, inv, csr);
    k_gemm<<<NB_GEMM, 256, 0, stream>>>(X, Wt, XWb);
    k_agg<<<(N_NODES + 3) / 4, 256, 0, stream>>>(XWb, csr, offs, deg, inv, out);
}